// Round 4
// baseline (105.915 us; speedup 1.0000x reference)
//
#include <hip/hip_runtime.h>
#include <hip/hip_bf16.h>

// SimCLR NT-Xent loss. B=4096, D=256, N=2B=8192 rows.
// loss = (1/N) sum_i [ log(denom_i) - log(pos_i) ]
//
// R16: denom-v2 "pipelined 4-tile blocks". R13/R15 proved atomics were NOT
// the cost (neutral). New theory: denom's one-shot stage->drain->compute
// convoy (no pipelining possible within a 1-tile block) is the ~38us.
// This version:
//  - 544 blocks, each owns 4 consecutive tiles of one block-row bi
//    (all <=768 resident at 3/CU -> single residency round, no R11
//    quantization; LDS stays 48KB -> 3 blocks/CU retained)
//  - A (128 rows, 32KB) staged ONCE per block, consumed to regs, reused
//    across 4 tiles (staging traffic 133MB -> 87MB)
//  - B streamed as 8 16KB halves through a 3-buffer rotation with counted
//    s_waitcnt vmcnt(8) (2 halves always in flight; never drain to 0
//    mid-loop; raw s_barrier, no compiler vmcnt(0) drains) [T3/T4]
//  - outputs: per-wave partials to P[64][64][2][128] f32 (4MB), every slot
//    single-writer (x<y row-partials of (x,y); x>y col-partials of (y,x);
//    s = wn for rows / wm for cols) -> no atomics, no init, no LDS parking
//    barriers; stores fire-and-forget inside the half loop.
// Invalid tail tiles of a row group are clamped to bj=63 (compute garbage,
// skip stores) to keep the unrolled loop + vmcnt immediates uniform.

#define NROWS 8192
#define BHALF 4096
#define DDIM  256

typedef __attribute__((ext_vector_type(4))) int   i32x4;
typedef __attribute__((ext_vector_type(8))) int   i32x8;
typedef __attribute__((ext_vector_type(4))) float f32x4;

#define SCALE1 0x7F7F7F7F               // e8m0 biased-127 = 2^0 in every byte
#define TWO_LOG2E 2.8853900817779268f   // 2/ln(2): exp(2x) = exp2(x*TWO_LOG2E)

__device__ __forceinline__ void load_lds16(const unsigned char* g, unsigned char* l) {
    __builtin_amdgcn_global_load_lds(
        (const __attribute__((address_space(1))) void*)g,
        (__attribute__((address_space(3))) void*)l, 16, 0, 0);
}

// Kernel 1: norms + fp8-normalized matrix + positive-pair log partials +
// out zero-init. (unchanged, verified)
__global__ __launch_bounds__(256) void prep_kernel(const float* __restrict__ z1,
                                                   const float* __restrict__ z2,
                                                   unsigned char* __restrict__ zn8,
                                                   float* __restrict__ posPart,
                                                   float* __restrict__ out) {
    __shared__ float sp[4];
    int wave = threadIdx.x >> 6;
    int lane = threadIdx.x & 63;
    int i    = blockIdx.x * 4 + wave;
    float4 a = reinterpret_cast<const float4*>(z1 + (size_t)i * DDIM)[lane];
    float4 b = reinterpret_cast<const float4*>(z2 + (size_t)i * DDIM)[lane];
    float ss1 = a.x * a.x + a.y * a.y + a.z * a.z + a.w * a.w;
    float ss2 = b.x * b.x + b.y * b.y + b.z * b.z + b.w * b.w;
    float dd  = a.x * b.x + a.y * b.y + a.z * b.z + a.w * b.w;
    #pragma unroll
    for (int off = 32; off; off >>= 1) {
        ss1 += __shfl_xor(ss1, off);
        ss2 += __shfl_xor(ss2, off);
        dd  += __shfl_xor(dd, off);
    }
    float n1 = fmaxf(sqrtf(ss1), 1e-8f);
    float n2 = fmaxf(sqrtf(ss2), 1e-8f);
    float i1 = 1.0f / n1, i2 = 1.0f / n2;
    int pa = __builtin_amdgcn_cvt_pk_fp8_f32(a.x * i1, a.y * i1, 0, 0);
    pa     = __builtin_amdgcn_cvt_pk_fp8_f32(a.z * i1, a.w * i1, pa, 1);
    int pb = __builtin_amdgcn_cvt_pk_fp8_f32(b.x * i2, b.y * i2, 0, 0);
    pb     = __builtin_amdgcn_cvt_pk_fp8_f32(b.z * i2, b.w * i2, pb, 1);
    reinterpret_cast<int*>(zn8 + (size_t)i * DDIM)[lane] = pa;
    reinterpret_cast<int*>(zn8 + (size_t)(i + BHALF) * DDIM)[lane] = pb;
    if (lane == 0) sp[wave] = __logf(dd * i1 * i2);
    if (blockIdx.x == 0 && threadIdx.x == 64) out[0] = 0.0f;
    __syncthreads();
    if (threadIdx.x == 0)
        posPart[blockIdx.x] = sp[0] + sp[1] + sp[2] + sp[3];
}

// Kernel 2: pipelined 4-tile denom blocks (see header comment).
__global__ __launch_bounds__(256, 3) void denom_kernel(const unsigned char* __restrict__ zn8,
                                                       float* __restrict__ P) {
    __shared__ __align__(16) unsigned char sMem[48 * 1024];
    unsigned char* buf0 = sMem;
    unsigned char* buf1 = sMem + 16384;
    unsigned char* buf2 = sMem + 32768;

    // block -> (bi, bjStart): row bi has ceil((64-bi)/4) groups of 4 tiles
    int b = blockIdx.x;
    int bi = 0;
    while (true) { int c = (67 - bi) >> 2; if (b < c) break; b -= c; bi++; }
    int bjStart = bi + b * 4;
    int iBase = bi * 128;

    int t    = threadIdx.x;
    int lane = t & 63;
    int wave = t >> 6;
    int col  = lane & 15;
    int quad = lane >> 4;
    int wm = wave >> 1, wn = wave & 1;

    // staging: row (q*16 + rowL) -> slab q*4096 + rowL*256; 16B slot (t&15)
    // holds k-chunk (t&15)^rowL (XOR swizzle, matched on read by ^col)
    int rowL  = t >> 4;
    int chunk = (t & 15) ^ rowL;

    unsigned char* bufs[3] = { buf0, buf1, buf2 };

    // stage 64 rows starting at global row R into a 16KB buffer (4 loads/thr)
    #define STAGE_HALF(R, DST)                                                  \
        {                                                                       \
            const unsigned char* _g = zn8 + (size_t)((R) + rowL) * DDIM + chunk * 16; \
            _Pragma("unroll")                                                   \
            for (int q = 0; q < 4; q++)                                         \
                load_lds16(_g + q * 4096, (DST) + t * 16 + q * 4096);           \
        }

    // ---- prologue: A halves -> buf0,buf1; B(tile0,half0) -> buf2 ----
    STAGE_HALF(iBase,          buf0);
    STAGE_HALF(iBase + 64,     buf1);
    STAGE_HALF(bjStart * 128,  buf2);
    asm volatile("s_waitcnt vmcnt(4)" ::: "memory");   // A landed (B0 flying)
    __builtin_amdgcn_s_barrier();

    // ---- A-fragments -> registers (held across all 4 tiles) ----
    i32x8 af[4][2];
    {
        const unsigned char* aRow = (wm ? buf1 : buf0) + (size_t)col * DDIM;
        #pragma unroll
        for (int mt = 0; mt < 4; mt++)
            #pragma unroll
            for (int ks = 0; ks < 2; ks++) {
                int g0 = ks * 8 + quad * 2;
                i32x4 lo = *(const i32x4*)(aRow + mt * 16 * DDIM + ((g0    ) ^ col) * 16);
                i32x4 hi = *(const i32x4*)(aRow + mt * 16 * DDIM + ((g0 + 1) ^ col) * 16);
                af[mt][ks] = __builtin_shufflevector(lo, hi, 0, 1, 2, 3, 4, 5, 6, 7);
            }
    }
    asm volatile("s_waitcnt lgkmcnt(0)" ::: "memory"); // A reads truly done
    __builtin_amdgcn_sched_barrier(0);                 // rule #18: pin the wait
    __builtin_amdgcn_s_barrier();                      // all waves done with A

    // ---- issue B(tile0,half1) -> buf0 (overwrites dead A-half0) ----
    STAGE_HALF(bjStart * 128 + 64, buf0);

    float rs[4][4];

    // ---- 8 halves: h = 2*tt + hh; buffer rotation bufOf(h) = (2+h)%3 ----
    #pragma unroll
    for (int k = 0; k < 8; k++) {
        const int tt = k >> 1, hh = k & 1;
        int bjv      = bjStart + tt;
        bool valid   = (bjv <= 63);
        int bj       = valid ? bjv : 63;           // clamp: compute, don't store
        int jBase    = bj * 128;
        bool isDiag  = (bi == bj);

        // issue stage for half s=min(k+2,7); tail re-stages are byte-identical
        {
            int s    = (k + 2 > 7) ? 7 : (k + 2);
            int tts  = s >> 1;
            int bjs_ = bjStart + tts;
            int bjs  = (bjs_ <= 63) ? bjs_ : 63;
            STAGE_HALF(bjs * 128 + (s & 1) * 64, bufs[(2 + s) % 3]);
        }

        asm volatile("s_waitcnt vmcnt(8)" ::: "memory"); // half k landed
        __builtin_amdgcn_s_barrier();

        const unsigned char* bRow = bufs[(2 + k) % 3] + (size_t)(wn * 32 + col) * DDIM;

        i32x8 bfr[2][2];
        #pragma unroll
        for (int nt = 0; nt < 2; nt++)
            #pragma unroll
            for (int ks = 0; ks < 2; ks++) {
                int g0 = ks * 8 + quad * 2;
                i32x4 lo = *(const i32x4*)(bRow + nt * 16 * DDIM + ((g0    ) ^ col) * 16);
                i32x4 hi = *(const i32x4*)(bRow + nt * 16 * DDIM + ((g0 + 1) ^ col) * 16);
                bfr[nt][ks] = __builtin_shufflevector(lo, hi, 0, 1, 2, 3, 4, 5, 6, 7);
            }

        if (hh == 0) {
            #pragma unroll
            for (int mt = 0; mt < 4; mt++)
                #pragma unroll
                for (int r = 0; r < 4; r++) rs[mt][r] = 0.f;
        }

        float cs[2] = {0.f, 0.f};
        #pragma unroll
        for (int mt = 0; mt < 4; mt++) {
            int gi = iBase + wm * 64 + mt * 16;
            #pragma unroll
            for (int nt = 0; nt < 2; nt++) {
                f32x4 acc = {0.f, 0.f, 0.f, 0.f};
                acc = __builtin_amdgcn_mfma_scale_f32_16x16x128_f8f6f4(
                          af[mt][0], bfr[nt][0], acc, 0, 0, 0, SCALE1, 0, SCALE1);
                acc = __builtin_amdgcn_mfma_scale_f32_16x16x128_f8f6f4(
                          af[mt][1], bfr[nt][1], acc, 0, 0, 0, SCALE1, 0, SCALE1);
                bool dtile = (gi == jBase + hh * 64 + wn * 32 + nt * 16);
                float csl = 0.f;
                #pragma unroll
                for (int r = 0; r < 4; r++) {
                    float e = exp2f(acc[r] * TWO_LOG2E);
                    if (dtile && (quad * 4 + r) == col) e = 0.f;
                    rs[mt][r] += e;
                    csl += e;
                }
                cs[nt] += csl;
            }
        }

        // col-partials of this half: reduce over quads, store per-wm partial
        // at slot (bj, bi, s=wm). Plain stores, single-writer.
        if (valid && !isDiag) {
            #pragma unroll
            for (int nt = 0; nt < 2; nt++) {
                float v = cs[nt];
                v += __shfl_xor(v, 16);
                v += __shfl_xor(v, 32);
                if (quad == 0)
                    P[(((size_t)bj * 64 + bi) * 2 + wm) * 128
                      + hh * 64 + wn * 32 + nt * 16 + col] = v;
            }
        }

        // tile boundary: row-partials, reduce 16 col-lanes, store per-wn
        // partial at slot (bi, bj, s=wn) as packed f32x4. Plain stores.
        if (hh == 1) {
            #pragma unroll
            for (int mt = 0; mt < 4; mt++)
                #pragma unroll
                for (int r = 0; r < 4; r++) {
                    float v = rs[mt][r];
                    v += __shfl_xor(v, 1);
                    v += __shfl_xor(v, 2);
                    v += __shfl_xor(v, 4);
                    v += __shfl_xor(v, 8);
                    rs[mt][r] = v;
                }
            if (valid && col == 0) {
                float* Pr = P + (((size_t)bi * 64 + bj) * 2 + wn) * 128;
                #pragma unroll
                for (int mt = 0; mt < 4; mt++) {
                    f32x4 v4 = { rs[mt][0], rs[mt][1], rs[mt][2], rs[mt][3] };
                    *reinterpret_cast<f32x4*>(Pr + wm * 64 + mt * 16 + quad * 4) = v4;
                }
            }
        }
    }
    #undef STAGE_HALF
}

// Kernel 3: per-row 128-slot reduction of P (coalesced, L2-resident) + final
// loss reduction, 32 blocks, atomic into prep-zeroed out[0].
__global__ __launch_bounds__(256) void loss_kernel(const float* __restrict__ posPart,
                                                   const float* __restrict__ P,
                                                   float* __restrict__ out) {
    __shared__ float sdata[4];
    int t = threadIdx.x;
    int i = blockIdx.x * 256 + t;
    int bi = i >> 7, r = i & 127;
    const float* p = P + ((size_t)bi << 14) + r;   // bi*64*2*128 + r
    float d0 = 0.f, d1 = 0.f, d2 = 0.f, d3 = 0.f;
    #pragma unroll
    for (int k = 0; k < 128; k += 4) {
        d0 += p[(k + 0) << 7];
        d1 += p[(k + 1) << 7];
        d2 += p[(k + 2) << 7];
        d3 += p[(k + 3) << 7];
    }
    float s = __logf((d0 + d1) + (d2 + d3));
    if (t < 32) s -= 2.0f * posPart[blockIdx.x * 32 + t];
    #pragma unroll
    for (int off = 32; off; off >>= 1) s += __shfl_xor(s, off);
    if ((t & 63) == 0) sdata[t >> 6] = s;
    __syncthreads();
    if (t == 0)
        atomicAdd(out, (sdata[0] + sdata[1] + sdata[2] + sdata[3]) * (1.0f / NROWS));
}

extern "C" void kernel_launch(void* const* d_in, const int* in_sizes, int n_in,
                              void* d_out, int out_size, void* d_ws, size_t ws_size,
                              hipStream_t stream) {
    const float* z1 = (const float*)d_in[0];
    const float* z2 = (const float*)d_in[1];

    // ws: zn8 fp8 [8192*256] (2 MB) | P f32[64][64][2][128] (4 MB) | posPart f32[1024]
    unsigned char* zn8 = (unsigned char*)d_ws;
    float* P       = (float*)((char*)d_ws + (size_t)NROWS * DDIM);
    float* posPart = P + (size_t)64 * 64 * 2 * 128;

    prep_kernel<<<BHALF / 4, 256, 0, stream>>>(z1, z2, zn8, posPart, (float*)d_out);
    denom_kernel<<<544, 256, 0, stream>>>(zn8, P);
    loss_kernel<<<NROWS / 256, 256, 0, stream>>>(posPart, P, (float*)d_out);
}

// Round 5
// 103.481 us; speedup vs baseline: 1.0235x; 1.0235x over previous
//
#include <hip/hip_runtime.h>
#include <hip/hip_bf16.h>

// SimCLR NT-Xent loss. B=4096, D=256, N=2B=8192 rows.
// loss = (1/N) sum_i [ log(denom_i) - log(pos_i) ]
//
// R17: denom-v3 "no-LDS". R16's counters: denom 47us with MfmaUtil 7%,
// VALU 22%, HBM 17%, Occupancy 16% -> pure latency/convoy bound, and
// FETCH_SIZE 31MB proves zn8 (2MB) is L2-resident: the whole LDS staging
// superstructure (global_load_lds, vmcnt, barriers, XOR swizzle) is
// overhead for data that never leaves L2 (guide Common-mistake #7).
// Key enabler: in GLOBAL memory each MFMA fragment's 32B is contiguous
// (the XOR-split existed only in LDS), so fragments load straight from
// L2 as one i32x8, line-coalesced per wave (16 rows x full 128B lines).
//
// Structure: 8256 independent 64x64 wave-tiles (triangular over 128
// strips; bijective 129x64 decode), 2064 blocks x 4 waves, no LDS, no
// barriers, no atomics. Per wave: A frags (64 VGPR) + B frags (64 VGPR)
// direct-loaded, 32 scaled-MFMAs, exp, row/col partials -> single-writer
// stores to P[128][128][64] f32 (4MB, no init). loss sums 128 slots/row.

#define NROWS 8192
#define BHALF 4096
#define DDIM  256

typedef __attribute__((ext_vector_type(4))) int   i32x4;
typedef __attribute__((ext_vector_type(8))) int   i32x8;
typedef __attribute__((ext_vector_type(4))) float f32x4;

#define SCALE1 0x7F7F7F7F               // e8m0 biased-127 = 2^0 in every byte
#define TWO_LOG2E 2.8853900817779268f   // 2/ln(2): exp(2x) = exp2(x*TWO_LOG2E)

// Kernel 1: norms + fp8-normalized matrix + positive-pair log partials +
// out zero-init. (unchanged, verified)
__global__ __launch_bounds__(256) void prep_kernel(const float* __restrict__ z1,
                                                   const float* __restrict__ z2,
                                                   unsigned char* __restrict__ zn8,
                                                   float* __restrict__ posPart,
                                                   float* __restrict__ out) {
    __shared__ float sp[4];
    int wave = threadIdx.x >> 6;
    int lane = threadIdx.x & 63;
    int i    = blockIdx.x * 4 + wave;
    float4 a = reinterpret_cast<const float4*>(z1 + (size_t)i * DDIM)[lane];
    float4 b = reinterpret_cast<const float4*>(z2 + (size_t)i * DDIM)[lane];
    float ss1 = a.x * a.x + a.y * a.y + a.z * a.z + a.w * a.w;
    float ss2 = b.x * b.x + b.y * b.y + b.z * b.z + b.w * b.w;
    float dd  = a.x * b.x + a.y * b.y + a.z * b.z + a.w * b.w;
    #pragma unroll
    for (int off = 32; off; off >>= 1) {
        ss1 += __shfl_xor(ss1, off);
        ss2 += __shfl_xor(ss2, off);
        dd  += __shfl_xor(dd, off);
    }
    float n1 = fmaxf(sqrtf(ss1), 1e-8f);
    float n2 = fmaxf(sqrtf(ss2), 1e-8f);
    float i1 = 1.0f / n1, i2 = 1.0f / n2;
    int pa = __builtin_amdgcn_cvt_pk_fp8_f32(a.x * i1, a.y * i1, 0, 0);
    pa     = __builtin_amdgcn_cvt_pk_fp8_f32(a.z * i1, a.w * i1, pa, 1);
    int pb = __builtin_amdgcn_cvt_pk_fp8_f32(b.x * i2, b.y * i2, 0, 0);
    pb     = __builtin_amdgcn_cvt_pk_fp8_f32(b.z * i2, b.w * i2, pb, 1);
    reinterpret_cast<int*>(zn8 + (size_t)i * DDIM)[lane] = pa;
    reinterpret_cast<int*>(zn8 + (size_t)(i + BHALF) * DDIM)[lane] = pb;
    if (lane == 0) sp[wave] = __logf(dd * i1 * i2);
    if (blockIdx.x == 0 && threadIdx.x == 64) out[0] = 0.0f;
    __syncthreads();
    if (threadIdx.x == 0)
        posPart[blockIdx.x] = sp[0] + sp[1] + sp[2] + sp[3];
}

// Kernel 2: no-LDS wave-independent 64x64 tiles (see header comment).
__global__ __launch_bounds__(256) void denom_kernel(const unsigned char* __restrict__ zn8,
                                                    float* __restrict__ P) {
    int t    = threadIdx.x;
    int lane = t & 63;
    int col  = lane & 15;
    int quad = lane >> 4;

    // global wave id -> triangular (ti, tj), 0 <= ti <= tj < 128
    int w = blockIdx.x * 4 + (t >> 6);      // [0, 8256)
    int y = w / 129, x = w - y * 129;       // grid 129 x 64
    int ti, tj;
    if (x > y) { ti = y;       tj = x - 1;   }
    else       { ti = 127 - y; tj = 127 - x; }
    int iBase = ti * 64, jBase = tj * 64;
    bool isDiag = (ti == tj);

    // direct L2 fragment loads: lane holds A rows (iBase + mt*16 + col),
    // k-bytes [ks*128 + quad*32, +32) — contiguous 32B in global memory.
    const unsigned char* aBase = zn8 + (size_t)(iBase + col) * DDIM + quad * 32;
    const unsigned char* bBase = zn8 + (size_t)(jBase + col) * DDIM + quad * 32;

    i32x8 af[4][2], bf[4][2];
    #pragma unroll
    for (int mt = 0; mt < 4; mt++)
        #pragma unroll
        for (int ks = 0; ks < 2; ks++) {
            af[mt][ks] = *(const i32x8*)(aBase + mt * 16 * DDIM + ks * 128);
            bf[mt][ks] = *(const i32x8*)(bBase + mt * 16 * DDIM + ks * 128);
        }

    float rs[4][4];                     // row-sums (C layout: row = quad*4+r)
    float cs[4];                        // col-sums per nt block (this lane's col)
    #pragma unroll
    for (int mt = 0; mt < 4; mt++)
        #pragma unroll
        for (int r = 0; r < 4; r++) rs[mt][r] = 0.f;
    #pragma unroll
    for (int nt = 0; nt < 4; nt++) cs[nt] = 0.f;

    #pragma unroll
    for (int mt = 0; mt < 4; mt++) {
        #pragma unroll
        for (int nt = 0; nt < 4; nt++) {
            f32x4 acc = {0.f, 0.f, 0.f, 0.f};
            acc = __builtin_amdgcn_mfma_scale_f32_16x16x128_f8f6f4(
                      af[mt][0], bf[nt][0], acc, 0, 0, 0, SCALE1, 0, SCALE1);
            acc = __builtin_amdgcn_mfma_scale_f32_16x16x128_f8f6f4(
                      af[mt][1], bf[nt][1], acc, 0, 0, 0, SCALE1, 0, SCALE1);
            bool dtile = isDiag && (mt == nt);
            #pragma unroll
            for (int r = 0; r < 4; r++) {
                float e = exp2f(acc[r] * TWO_LOG2E);
                if (dtile && (quad * 4 + r) == col) e = 0.f;
                rs[mt][r] += e;
                cs[nt]    += e;
            }
        }
    }

    // row partials: reduce over the 16 col-lanes within each quad
    #pragma unroll
    for (int mt = 0; mt < 4; mt++)
        #pragma unroll
        for (int r = 0; r < 4; r++) {
            float v = rs[mt][r];
            v += __shfl_xor(v, 1);
            v += __shfl_xor(v, 2);
            v += __shfl_xor(v, 4);
            v += __shfl_xor(v, 8);
            rs[mt][r] = v;
        }
    if (col == 0) {
        float* Prow = P + ((size_t)ti * 128 + tj) * 64;
        #pragma unroll
        for (int mt = 0; mt < 4; mt++) {
            f32x4 v4 = { rs[mt][0], rs[mt][1], rs[mt][2], rs[mt][3] };
            *reinterpret_cast<f32x4*>(Prow + mt * 16 + quad * 4) = v4;
        }
    }

    // col partials: reduce over quads; store at transposed slot (tj, ti)
    if (!isDiag) {
        float* Pcol = P + ((size_t)tj * 128 + ti) * 64;
        #pragma unroll
        for (int nt = 0; nt < 4; nt++) {
            float v = cs[nt];
            v += __shfl_xor(v, 16);
            v += __shfl_xor(v, 32);
            if (quad == 0)
                Pcol[nt * 16 + col] = v;
        }
    }
}

// Kernel 3: per-row 128-slot reduction of P (coalesced, L2-resident) + final
// loss reduction, 32 blocks, atomic into prep-zeroed out[0].
__global__ __launch_bounds__(256) void loss_kernel(const float* __restrict__ posPart,
                                                   const float* __restrict__ P,
                                                   float* __restrict__ out) {
    __shared__ float sdata[4];
    int t = threadIdx.x;
    int i = blockIdx.x * 256 + t;
    int bi = i >> 6, r = i & 63;
    const float* p = P + ((size_t)bi << 13) + r;   // bi*128*64 + r
    float d0 = 0.f, d1 = 0.f, d2 = 0.f, d3 = 0.f;
    #pragma unroll
    for (int k = 0; k < 128; k += 4) {
        d0 += p[(k + 0) << 6];
        d1 += p[(k + 1) << 6];
        d2 += p[(k + 2) << 6];
        d3 += p[(k + 3) << 6];
    }
    float s = __logf((d0 + d1) + (d2 + d3));
    if (t < 32) s -= 2.0f * posPart[blockIdx.x * 32 + t];
    #pragma unroll
    for (int off = 32; off; off >>= 1) s += __shfl_xor(s, off);
    if ((t & 63) == 0) sdata[t >> 6] = s;
    __syncthreads();
    if (t == 0)
        atomicAdd(out, (sdata[0] + sdata[1] + sdata[2] + sdata[3]) * (1.0f / NROWS));
}

extern "C" void kernel_launch(void* const* d_in, const int* in_sizes, int n_in,
                              void* d_out, int out_size, void* d_ws, size_t ws_size,
                              hipStream_t stream) {
    const float* z1 = (const float*)d_in[0];
    const float* z2 = (const float*)d_in[1];

    // ws: zn8 fp8 [8192*256] (2 MB) | P f32[128][128][64] (4 MB) | posPart f32[1024]
    unsigned char* zn8 = (unsigned char*)d_ws;
    float* P       = (float*)((char*)d_ws + (size_t)NROWS * DDIM);
    float* posPart = P + (size_t)128 * 128 * 64;

    prep_kernel<<<BHALF / 4, 256, 0, stream>>>(z1, z2, zn8, posPart, (float*)d_out);
    denom_kernel<<<2064, 256, 0, stream>>>(zn8, P);
    loss_kernel<<<NROWS / 256, 256, 0, stream>>>(posPart, P, (float*)d_out);
}